// Round 16
// baseline (62.077 us; speedup 1.0000x reference)
//
#include <hip/hip_runtime.h>

// SimpleHybridModel via MFMA, all-transposed chaining:
//  conv1d(k=3,SAME,relu) -> SimpleRNN(16,tanh) -> dense(8,relu) -> dense(1)
//
// R16: 4 recurrence chains per lane (fused loop), BLK=128.
// Evidence: per-wave work/latency cuts paid linearly (R6->R12: 54.9->43.6);
// occupancy/pipeline changes were neutral (R13/R14/R15). The serial
// MFMA(AU,H)+tanh chain (~60-90cy x 20) is the exposed latency; 1->2 chains
// gave +6% (R11->R12). This round: 4 independent chains interleaved per lane.
// Fused loop (B2 consumed immediately -> no B2s register arrays).
//  - 128 elems/block, 2 waves; chain c elem = wave*64 + c*16 + b16.
//  - one LDS base; ds_read offsets c*16*EPW + 4*l are compile-time (fold
//    into the 16-bit ds offset immediate; max 16432B < 64KB).
//  - staging: thread e=tid owns elem e: 5 rounds x {7 float4, 16 pkrtz,
//    4 aligned ds_write_b128} -> rowized 21-slot layout.
// Retained: 21-slot shared-pad layout (slot0 pad (0..0,1.0h); slot l+g read;
// row-20 read of elem e = pad slot of elem e+1; 2 guard slots for elem 127;
// every real row carries dummy 1.0 at half 7 -> g=3 bias tap is exact),
// conv bias rides MFMA k=31, 2*log2e folded into A2/AU/rnn_b, rcp+exp2 tanh,
// packed cvts, head via MFMA.

#define BLK 128
#define LSEQ 20
#define EPB 128           // elements per block
#define EPW 84            // dwords per element: 21 slots * 4
#define LOG2E2 2.8853900817779268f

typedef _Float16 f16;
typedef __fp16   fp16x2 __attribute__((ext_vector_type(2)));
typedef _Float16 f16x4 __attribute__((ext_vector_type(4)));
typedef _Float16 f16x8 __attribute__((ext_vector_type(8)));
typedef float    f32x4 __attribute__((ext_vector_type(4)));

union UB128 { uint4 q; f16x8 v; };
union UB64  { f16x4 v; fp16x2 p[2]; };
union HU    { fp16x2 p; uint u; };

__global__ __launch_bounds__(BLK, 2) void hybrid_fwd(
    const float* __restrict__ x,
    const float* __restrict__ conv_w, const float* __restrict__ conv_b,
    const float* __restrict__ rnn_w,  const float* __restrict__ rnn_u,
    const float* __restrict__ rnn_b,
    const float* __restrict__ d1_w,   const float* __restrict__ d1_b,
    const float* __restrict__ out_w,  const float* __restrict__ out_b,
    float* __restrict__ out)
{
    __shared__ __align__(16) uint xs[EPB * EPW + 8];   // 43040 B + guards

    const int tid  = threadIdx.x;
    const int wave = tid >> 6, lane = tid & 63;
    const int b16  = lane & 15, g = lane >> 4;
    const long BE  = (long)blockIdx.x * EPB;

    // ---- pad slot 0 of each element + 2 guard slots: (0,...,0, 1.0h) ----
    const uint4 PAD = make_uint4(0u, 0u, 0u, 0x3C000000u);
    *(uint4*)(xs + tid * EPW) = PAD;                       // tid == elem
    if (tid < 2) *(uint4*)(xs + EPB * EPW + 4 * tid) = PAD;

    // ---- stage x: thread owns elem tid; 5 rounds of 4 rows ----
    {
        const float4* src = (const float4*)(x + (BE + tid) * 140);
        uint* eb = xs + tid * EPW;
        #pragma unroll
        for (int k = 0; k < 5; ++k) {
            float4 v[7];
            #pragma unroll
            for (int j = 0; j < 7; ++j) v[j] = src[7 * k + j];
            const float* f = (const float*)v;              // 28 floats, static
            #pragma unroll
            for (int i = 0; i < 4; ++i) {                  // row 4k+i
                HU h0, h1, h2, h3;
                h0.p = __builtin_amdgcn_cvt_pkrtz(f[7 * i + 0], f[7 * i + 1]);
                h1.p = __builtin_amdgcn_cvt_pkrtz(f[7 * i + 2], f[7 * i + 3]);
                h2.p = __builtin_amdgcn_cvt_pkrtz(f[7 * i + 4], f[7 * i + 5]);
                h3.p = __builtin_amdgcn_cvt_pkrtz(f[7 * i + 6], 1.0f);
                uint4 val; val.x = h0.u; val.y = h1.u; val.z = h2.u; val.w = h3.u;
                *(uint4*)(eb + 4 * (4 * k + i + 1)) = val;  // slot r+1, 16B
            }
        }
    }

    // ---- weight fragments (once per block; overlap staging latency) ----
    f16x8 A1;
    #pragma unroll
    for (int t = 0; t < 8; ++t) {
        float wv = conv_w[min(g * 7 + t, 20) * 16 + b16];
        float sel = (g < 3 && t < 7) ? wv
                  : ((g == 3 && t == 7) ? conv_b[b16] : 0.f);
        A1[t] = (f16)sel;
    }
    f16x4 A2, AU;
    f32x4 rbp;
    #pragma unroll
    for (int t = 0; t < 4; ++t) {
        A2[t]  = (f16)(LOG2E2 * rnn_w[(4 * g + t) * 16 + b16]);
        AU[t]  = (f16)(LOG2E2 * rnn_u[(4 * g + t) * 16 + b16]);
        rbp[t] = LOG2E2 * rnn_b[4 * g + t];
    }
    f16x4 A3;
    f32x4 c3;
    #pragma unroll
    for (int t = 0; t < 4; ++t) {
        int j = 4 * g + t;
        A3[t] = (f16)(b16 < 8 ? d1_w[j * 8 + b16] : 0.f);
        c3[t] = d1_b[min(j, 7)];
    }
    float ow[4];
    #pragma unroll
    for (int r = 0; r < 4; ++r)
        ow[r] = (g < 2) ? out_w[min(4 * g + r, 7)] : 0.f;
    const float ob = out_b[0];
    const f32x4 zero4 = {0.f, 0.f, 0.f, 0.f};

    __syncthreads();

    // single base; chain c, step l: offset c*16*EPW + 4*l (compile-time)
    const uint* rbase = xs + ((wave << 6) + b16) * EPW + 4 * g;

    // ---- fused loop: 4 independent chains interleaved ----
    f16x4 H[4] = {{}, {}, {}, {}};
    #pragma unroll
    for (int l = 0; l < LSEQ; ++l) {
        #pragma unroll
        for (int c = 0; c < 4; ++c) {
            UB128 B1;
            B1.q = *(const uint4*)(rbase + c * 16 * EPW + 4 * l);
            f32x4 a1 = __builtin_amdgcn_mfma_f32_16x16x32_f16(A1, B1.v, zero4, 0, 0, 0);
            UB64 B2;
            B2.p[0] = __builtin_amdgcn_cvt_pkrtz(fmaxf(a1[0], 0.f), fmaxf(a1[1], 0.f));
            B2.p[1] = __builtin_amdgcn_cvt_pkrtz(fmaxf(a1[2], 0.f), fmaxf(a1[3], 0.f));
            f32x4 a2 = __builtin_amdgcn_mfma_f32_16x16x16f16(A2, B2.v, rbp, 0, 0, 0);
            a2 = __builtin_amdgcn_mfma_f32_16x16x16f16(AU, H[c], a2, 0, 0, 0);
            float t0 = __builtin_amdgcn_rcpf(1.f + __builtin_amdgcn_exp2f(a2[0]));
            float t1 = __builtin_amdgcn_rcpf(1.f + __builtin_amdgcn_exp2f(a2[1]));
            float t2 = __builtin_amdgcn_rcpf(1.f + __builtin_amdgcn_exp2f(a2[2]));
            float t3 = __builtin_amdgcn_rcpf(1.f + __builtin_amdgcn_exp2f(a2[3]));
            UB64 Hn;
            Hn.p[0] = __builtin_amdgcn_cvt_pkrtz(fmaf(-2.f, t0, 1.f), fmaf(-2.f, t1, 1.f));
            Hn.p[1] = __builtin_amdgcn_cvt_pkrtz(fmaf(-2.f, t2, 1.f), fmaf(-2.f, t3, 1.f));
            H[c] = Hn.v;
        }
    }

    // ---- head via MFMA, 4 chains ----
    float p[4];
    #pragma unroll
    for (int c = 0; c < 4; ++c) {
        f32x4 a3 = __builtin_amdgcn_mfma_f32_16x16x16f16(A3, H[c], c3, 0, 0, 0);
        float part = 0.f;
        #pragma unroll
        for (int r = 0; r < 4; ++r)
            part = fmaf(fmaxf(a3[r], 0.f), ow[r], part);
        part += __shfl_xor(part, 16);
        part += __shfl_xor(part, 32);
        p[c] = part;
    }
    if (lane < 16) {
        #pragma unroll
        for (int c = 0; c < 4; ++c)
            out[BE + (wave << 6) + c * 16 + b16] = p[c] + ob;
    }
}

extern "C" void kernel_launch(void* const* d_in, const int* in_sizes, int n_in,
                              void* d_out, int out_size, void* d_ws, size_t ws_size,
                              hipStream_t stream) {
    const float* x      = (const float*)d_in[0];
    const float* conv_w = (const float*)d_in[1];
    const float* conv_b = (const float*)d_in[2];
    const float* rnn_w  = (const float*)d_in[3];
    const float* rnn_u  = (const float*)d_in[4];
    const float* rnn_b  = (const float*)d_in[5];
    const float* d1_w   = (const float*)d_in[6];
    const float* d1_b   = (const float*)d_in[7];
    const float* out_w  = (const float*)d_in[8];
    const float* out_b  = (const float*)d_in[9];
    float* out = (float*)d_out;

    const int B = out_size;                 // 262144
    const int grid = B / EPB;               // 2048 blocks
    hybrid_fwd<<<grid, BLK, 0, stream>>>(x, conv_w, conv_b, rnn_w, rnn_u, rnn_b,
                                         d1_w, d1_b, out_w, out_b, out);
}

// Round 17
// 47.379 us; speedup vs baseline: 1.3102x; 1.3102x over previous
//
#include <hip/hip_runtime.h>

// SimpleHybridModel via MFMA, all-transposed chaining:
//  conv1d(k=3,SAME,relu) -> SimpleRNN(16,tanh) -> dense(8,relu) -> dense(1)
//
// R17 = R12 (best, 43.6us) with the block barrier DISSOLVED:
//  - Evidence: {12 waves x 2 chains}=43.6 ~= {24 waves x 1 chain}=47 ~= all
//    configs (44-50) with every pipe <50% busy -> plateau is structural:
//    lockstep block phases (all waves stage -> barrier -> all compute) force
//    resident blocks into alternating memory-only/compute-only regimes.
//  - Fix: wave-local staging. Each wave stages its own 32 elems into a
//    self-contained LDS region (own pad slot0 per elem + 2 guard slots; no
//    cross-wave sharing) -> NO __syncthreads; only s_waitcnt lgkmcnt(0) +
//    sched_barrier(0) (rule #18) before compute. 12 resident waves desync,
//    interleaving VMEM and VALU/MFMA naturally.
// Retained from R12/R13: BLK=256, 2 chains/lane, phase-split full unroll,
// float2 staging (2 threads/elem), global weight fragments, 21-slot layout
// (slot0 pad (0..0,1.0h); slot l+g read as one aligned ds_read_b128; row-20
// read = next elem's pad; every row carries dummy 1.0 at half 7 so the
// k=31 conv-bias tap is exact), 2*log2e folded into A2/AU/rnn_b, rcp+exp2
// tanh, packed cvts, head via MFMA.

#define BLK 256
#define LSEQ 20
#define EPW 84              // dwords per element: 21 slots * 4
#define WREG (32*EPW + 8)   // 2696 dwords per wave region (32 elems + 2 guards)
#define LOG2E2 2.8853900817779268f

typedef _Float16 f16;
typedef __fp16   fp16x2 __attribute__((ext_vector_type(2)));
typedef _Float16 f16x4 __attribute__((ext_vector_type(4)));
typedef _Float16 f16x8 __attribute__((ext_vector_type(8)));
typedef float    f32x4 __attribute__((ext_vector_type(4)));

union UB128 { uint4 q; f16x8 v; };
union UB64  { f16x4 v; fp16x2 p[2]; };
union HU    { fp16x2 p; uint u; };

__global__ __launch_bounds__(BLK, 4) void hybrid_fwd(
    const float* __restrict__ x,
    const float* __restrict__ conv_w, const float* __restrict__ conv_b,
    const float* __restrict__ rnn_w,  const float* __restrict__ rnn_u,
    const float* __restrict__ rnn_b,
    const float* __restrict__ d1_w,   const float* __restrict__ d1_b,
    const float* __restrict__ out_w,  const float* __restrict__ out_b,
    float* __restrict__ out)
{
    __shared__ __align__(16) uint xs[4 * WREG];   // 43136 B

    const int tid  = threadIdx.x;
    const int wave = tid >> 6, lane = tid & 63;
    const int b16  = lane & 15, g = lane >> 4;
    const long BE  = (long)blockIdx.x * 128;      // block's first elem

    uint* wb = xs + wave * WREG;                  // this wave's region

    // ---- wave-local pads: slot0 of each of my 32 elems + 2 guard slots ----
    const uint4 PAD = make_uint4(0u, 0u, 0u, 0x3C000000u);
    const int e = lane >> 1;                      // my elem (0..31 in wave)
    const int q = lane & 1;                       // half: rows 10q..10q+9
    if (q == 0) *(uint4*)(wb + e * EPW) = PAD;
    if (lane < 2) *(uint4*)(wb + 32 * EPW + 4 * lane) = PAD;

    // ---- wave-local staging: 2 threads/elem, 35 float2 each ----
    {
        const float2* sp = (const float2*)(x + (BE + wave * 32 + e) * 140 + q * 70);
        float2 f2[35];
        #pragma unroll
        for (int i = 0; i < 35; ++i) f2[i] = sp[i];
        const float* f = (const float*)f2;        // static-indexed
        uint* eb = wb + e * EPW;
        #pragma unroll
        for (int i = 0; i < 10; ++i) {            // row r = 10q+i -> slot r+1
            HU h0, h1, h2, h3;
            h0.p = __builtin_amdgcn_cvt_pkrtz(f[7 * i + 0], f[7 * i + 1]);
            h1.p = __builtin_amdgcn_cvt_pkrtz(f[7 * i + 2], f[7 * i + 3]);
            h2.p = __builtin_amdgcn_cvt_pkrtz(f[7 * i + 4], f[7 * i + 5]);
            h3.p = __builtin_amdgcn_cvt_pkrtz(f[7 * i + 6], 1.0f);   // dummy
            uint4 val; val.x = h0.u; val.y = h1.u; val.z = h2.u; val.w = h3.u;
            *(uint4*)(eb + 4 * (10 * q + i + 1)) = val;   // 16B aligned
        }
    }

    // ---- weight fragments (VMEM latency overlaps staging) ----
    f16x8 A1;
    #pragma unroll
    for (int t = 0; t < 8; ++t) {
        float wv = conv_w[min(g * 7 + t, 20) * 16 + b16];
        float sel = (g < 3 && t < 7) ? wv
                  : ((g == 3 && t == 7) ? conv_b[b16] : 0.f);
        A1[t] = (f16)sel;
    }
    f16x4 A2, AU;
    f32x4 rbp;
    #pragma unroll
    for (int t = 0; t < 4; ++t) {
        A2[t]  = (f16)(LOG2E2 * rnn_w[(4 * g + t) * 16 + b16]);
        AU[t]  = (f16)(LOG2E2 * rnn_u[(4 * g + t) * 16 + b16]);
        rbp[t] = LOG2E2 * rnn_b[4 * g + t];
    }
    f16x4 A3;
    f32x4 c3;
    #pragma unroll
    for (int t = 0; t < 4; ++t) {
        int j = 4 * g + t;
        A3[t] = (f16)(b16 < 8 ? d1_w[j * 8 + b16] : 0.f);
        c3[t] = d1_b[min(j, 7)];
    }
    float ow[4];
    #pragma unroll
    for (int r = 0; r < 4; ++r)
        ow[r] = (g < 2) ? out_w[min(4 * g + r, 7)] : 0.f;
    const float ob = out_b[0];
    const f32x4 zero4 = {0.f, 0.f, 0.f, 0.f};

    // ---- wave-local fence instead of __syncthreads (rule #18) ----
    asm volatile("s_waitcnt lgkmcnt(0)" ::: "memory");
    __builtin_amdgcn_sched_barrier(0);

    // read bases; chain c elem = wave*32 + c*16 + b16; step l: +4l dwords
    const uint* rb0 = wb + b16 * EPW + 4 * g;
    const uint* rb1 = rb0 + 16 * EPW;

    // ---- Phase A: conv + relu, both chains, full unroll ----
    f16x4 B2sA[LSEQ], B2sB[LSEQ];
    #pragma unroll
    for (int l = 0; l < LSEQ; ++l) {
        UB128 B1a, B1b;
        B1a.q = *(const uint4*)(rb0 + 4 * l);
        B1b.q = *(const uint4*)(rb1 + 4 * l);
        f32x4 a1a = __builtin_amdgcn_mfma_f32_16x16x32_f16(A1, B1a.v, zero4, 0, 0, 0);
        f32x4 a1b = __builtin_amdgcn_mfma_f32_16x16x32_f16(A1, B1b.v, zero4, 0, 0, 0);
        UB64 Ba, Bb;
        Ba.p[0] = __builtin_amdgcn_cvt_pkrtz(fmaxf(a1a[0], 0.f), fmaxf(a1a[1], 0.f));
        Ba.p[1] = __builtin_amdgcn_cvt_pkrtz(fmaxf(a1a[2], 0.f), fmaxf(a1a[3], 0.f));
        Bb.p[0] = __builtin_amdgcn_cvt_pkrtz(fmaxf(a1b[0], 0.f), fmaxf(a1b[1], 0.f));
        Bb.p[1] = __builtin_amdgcn_cvt_pkrtz(fmaxf(a1b[2], 0.f), fmaxf(a1b[3], 0.f));
        B2sA[l] = Ba.v;
        B2sB[l] = Bb.v;
    }

    // ---- Phase B: two independent serial recurrences, interleaved ----
    f16x4 H0 = {}, H1 = {};
    #pragma unroll
    for (int l = 0; l < LSEQ; ++l) {
        f32x4 a20 = __builtin_amdgcn_mfma_f32_16x16x16f16(A2, B2sA[l], rbp, 0, 0, 0);
        f32x4 a21 = __builtin_amdgcn_mfma_f32_16x16x16f16(A2, B2sB[l], rbp, 0, 0, 0);
        a20 = __builtin_amdgcn_mfma_f32_16x16x16f16(AU, H0, a20, 0, 0, 0);
        a21 = __builtin_amdgcn_mfma_f32_16x16x16f16(AU, H1, a21, 0, 0, 0);
        float t00 = __builtin_amdgcn_rcpf(1.f + __builtin_amdgcn_exp2f(a20[0]));
        float t01 = __builtin_amdgcn_rcpf(1.f + __builtin_amdgcn_exp2f(a20[1]));
        float t02 = __builtin_amdgcn_rcpf(1.f + __builtin_amdgcn_exp2f(a20[2]));
        float t03 = __builtin_amdgcn_rcpf(1.f + __builtin_amdgcn_exp2f(a20[3]));
        float t10 = __builtin_amdgcn_rcpf(1.f + __builtin_amdgcn_exp2f(a21[0]));
        float t11 = __builtin_amdgcn_rcpf(1.f + __builtin_amdgcn_exp2f(a21[1]));
        float t12 = __builtin_amdgcn_rcpf(1.f + __builtin_amdgcn_exp2f(a21[2]));
        float t13 = __builtin_amdgcn_rcpf(1.f + __builtin_amdgcn_exp2f(a21[3]));
        UB64 Hn0, Hn1;
        Hn0.p[0] = __builtin_amdgcn_cvt_pkrtz(fmaf(-2.f, t00, 1.f), fmaf(-2.f, t01, 1.f));
        Hn0.p[1] = __builtin_amdgcn_cvt_pkrtz(fmaf(-2.f, t02, 1.f), fmaf(-2.f, t03, 1.f));
        Hn1.p[0] = __builtin_amdgcn_cvt_pkrtz(fmaf(-2.f, t10, 1.f), fmaf(-2.f, t11, 1.f));
        Hn1.p[1] = __builtin_amdgcn_cvt_pkrtz(fmaf(-2.f, t12, 1.f), fmaf(-2.f, t13, 1.f));
        H0 = Hn0.v;
        H1 = Hn1.v;
    }

    // ---- head via MFMA ----
    f32x4 a30 = __builtin_amdgcn_mfma_f32_16x16x16f16(A3, H0, c3, 0, 0, 0);
    f32x4 a31 = __builtin_amdgcn_mfma_f32_16x16x16f16(A3, H1, c3, 0, 0, 0);
    float p0 = 0.f, p1 = 0.f;
    #pragma unroll
    for (int r = 0; r < 4; ++r) {
        p0 = fmaf(fmaxf(a30[r], 0.f), ow[r], p0);
        p1 = fmaf(fmaxf(a31[r], 0.f), ow[r], p1);
    }
    p0 += __shfl_xor(p0, 16); p0 += __shfl_xor(p0, 32);
    p1 += __shfl_xor(p1, 16); p1 += __shfl_xor(p1, 32);
    if (lane < 16) {
        out[BE + wave * 32 + b16]      = p0 + ob;
        out[BE + wave * 32 + 16 + b16] = p1 + ob;
    }
}

extern "C" void kernel_launch(void* const* d_in, const int* in_sizes, int n_in,
                              void* d_out, int out_size, void* d_ws, size_t ws_size,
                              hipStream_t stream) {
    const float* x      = (const float*)d_in[0];
    const float* conv_w = (const float*)d_in[1];
    const float* conv_b = (const float*)d_in[2];
    const float* rnn_w  = (const float*)d_in[3];
    const float* rnn_u  = (const float*)d_in[4];
    const float* rnn_b  = (const float*)d_in[5];
    const float* d1_w   = (const float*)d_in[6];
    const float* d1_b   = (const float*)d_in[7];
    const float* out_w  = (const float*)d_in[8];
    const float* out_b  = (const float*)d_in[9];
    float* out = (float*)d_out;

    const int B = out_size;                 // 262144
    const int grid = B / 128;               // 2048 blocks
    hybrid_fwd<<<grid, BLK, 0, stream>>>(x, conv_w, conv_b, rnn_w, rnn_u, rnn_b,
                                         d1_w, d1_b, out_w, out_b, out);
}

// Round 18
// 39.736 us; speedup vs baseline: 1.5622x; 1.1924x over previous
//
#include <hip/hip_runtime.h>

// SimpleHybridModel via MFMA, all-transposed chaining:
//  conv1d(k=3,SAME,relu) -> SimpleRNN(16,tanh) -> dense(8,relu) -> dense(1)
//
// R18: single-wave blocks to maximize RESIDENT ELEMENTS per CU.
// Unifying observation from R9-R17: resident elems/CU ~= 384 in every config
// (LDS/elem fixed at 336B; blocks/CU LDS-capped) and throughput ~= resident
// elems / T_elem with T_elem latency-dominated (all pipes <50%). So raise
// residency: BLK=64, 32 elems/block, LDS 10.8KB -> 14 blocks/CU = 448 elems
// (+17%). No __syncthreads anywhere (wave-internal staging; lgkmcnt fence +
// sched_barrier, rule #18).
// Also: staging lane remap (elem=lane&31, half=lane>>5) -> ds_write_b128
// bank-quads (5*lane+s) mod 8 distinct per 8-lane phase = CONFLICT-FREE
// (R12's pair-interleave was the measured 2M conflict cycles).
// Retained from R12: 2 chains/lane, phase-split full unroll, 21-slot f16
// element layout (slot0 pad (0..0,1.0h); slot l+g read as one aligned
// ds_read_b128; elem e row-20 read = elem e+1's pad slot; dummy 1.0 at
// half 7 of every row feeds the k=31 conv-bias tap), conv bias rides MFMA,
// 2*log2e folded into A2/AU/rnn_b, rcp+exp2 tanh, packed cvts, head via MFMA.

#define BLK 64
#define LSEQ 20
#define EPW 84              // dwords per element: 21 slots * 4
#define LOG2E2 2.8853900817779268f

typedef _Float16 f16;
typedef __fp16   fp16x2 __attribute__((ext_vector_type(2)));
typedef _Float16 f16x4 __attribute__((ext_vector_type(4)));
typedef _Float16 f16x8 __attribute__((ext_vector_type(8)));
typedef float    f32x4 __attribute__((ext_vector_type(4)));

union UB128 { uint4 q; f16x8 v; };
union UB64  { f16x4 v; fp16x2 p[2]; };
union HU    { fp16x2 p; uint u; };

__global__ __launch_bounds__(BLK, 4) void hybrid_fwd(
    const float* __restrict__ x,
    const float* __restrict__ conv_w, const float* __restrict__ conv_b,
    const float* __restrict__ rnn_w,  const float* __restrict__ rnn_u,
    const float* __restrict__ rnn_b,
    const float* __restrict__ d1_w,   const float* __restrict__ d1_b,
    const float* __restrict__ out_w,  const float* __restrict__ out_b,
    float* __restrict__ out)
{
    __shared__ __align__(16) uint xs[32 * EPW + 8];   // 10784 B

    const int lane = threadIdx.x;                 // single wave
    const int b16  = lane & 15, g = lane >> 4;
    const long BE  = (long)blockIdx.x * 32;       // block's first elem

    // ---- weight fragments FIRST (VMEM latency overlaps staging below) ----
    f16x8 A1;
    #pragma unroll
    for (int t = 0; t < 8; ++t) {
        float wv = conv_w[min(g * 7 + t, 20) * 16 + b16];
        float sel = (g < 3 && t < 7) ? wv
                  : ((g == 3 && t == 7) ? conv_b[b16] : 0.f);
        A1[t] = (f16)sel;
    }
    f16x4 A2, AU;
    f32x4 rbp;
    #pragma unroll
    for (int t = 0; t < 4; ++t) {
        A2[t]  = (f16)(LOG2E2 * rnn_w[(4 * g + t) * 16 + b16]);
        AU[t]  = (f16)(LOG2E2 * rnn_u[(4 * g + t) * 16 + b16]);
        rbp[t] = LOG2E2 * rnn_b[4 * g + t];
    }
    f16x4 A3;
    f32x4 c3;
    #pragma unroll
    for (int t = 0; t < 4; ++t) {
        int j = 4 * g + t;
        A3[t] = (f16)(b16 < 8 ? d1_w[j * 8 + b16] : 0.f);
        c3[t] = d1_b[min(j, 7)];
    }
    float ow[4];
    #pragma unroll
    for (int r = 0; r < 4; ++r)
        ow[r] = (g < 2) ? out_w[min(4 * g + r, 7)] : 0.f;
    const float ob = out_b[0];
    const f32x4 zero4 = {0.f, 0.f, 0.f, 0.f};

    // ---- pads: slot0 of each elem (lanes<32) + 2 guard slots ----
    const uint4 PAD = make_uint4(0u, 0u, 0u, 0x3C000000u);
    const int e = lane & 31;                      // staged elem
    const int h = lane >> 5;                      // half: rows 10h..10h+9
    if (h == 0) *(uint4*)(xs + e * EPW) = PAD;
    if (lane < 2) *(uint4*)(xs + 32 * EPW + 4 * lane) = PAD;

    // ---- stage x: conflict-free writes (bank-quad (5*lane+s) mod 8) ----
    {
        const float2* sp = (const float2*)(x + (BE + e) * 140 + h * 70);
        float2 f2[35];
        #pragma unroll
        for (int i = 0; i < 35; ++i) f2[i] = sp[i];
        const float* f = (const float*)f2;        // static-indexed
        uint* eb = xs + e * EPW;
        #pragma unroll
        for (int i = 0; i < 10; ++i) {            // row r = 10h+i -> slot r+1
            HU h0, h1, h2, h3;
            h0.p = __builtin_amdgcn_cvt_pkrtz(f[7 * i + 0], f[7 * i + 1]);
            h1.p = __builtin_amdgcn_cvt_pkrtz(f[7 * i + 2], f[7 * i + 3]);
            h2.p = __builtin_amdgcn_cvt_pkrtz(f[7 * i + 4], f[7 * i + 5]);
            h3.p = __builtin_amdgcn_cvt_pkrtz(f[7 * i + 6], 1.0f);   // dummy
            uint4 val; val.x = h0.u; val.y = h1.u; val.z = h2.u; val.w = h3.u;
            *(uint4*)(eb + 4 * (10 * h + i + 1)) = val;   // 16B aligned
        }
    }

    // ---- wave-local fence (single-wave block: no __syncthreads needed) ----
    asm volatile("s_waitcnt lgkmcnt(0)" ::: "memory");
    __builtin_amdgcn_sched_barrier(0);

    // read bases; chain c elem = c*16 + b16; step l: +16B; conflict-free
    const uint* rb0 = xs + b16 * EPW + 4 * g;
    const uint* rb1 = rb0 + 16 * EPW;

    // ---- Phase A: conv + relu, both chains, full unroll ----
    f16x4 B2sA[LSEQ], B2sB[LSEQ];
    #pragma unroll
    for (int l = 0; l < LSEQ; ++l) {
        UB128 B1a, B1b;
        B1a.q = *(const uint4*)(rb0 + 4 * l);
        B1b.q = *(const uint4*)(rb1 + 4 * l);
        f32x4 a1a = __builtin_amdgcn_mfma_f32_16x16x32_f16(A1, B1a.v, zero4, 0, 0, 0);
        f32x4 a1b = __builtin_amdgcn_mfma_f32_16x16x32_f16(A1, B1b.v, zero4, 0, 0, 0);
        UB64 Ba, Bb;
        Ba.p[0] = __builtin_amdgcn_cvt_pkrtz(fmaxf(a1a[0], 0.f), fmaxf(a1a[1], 0.f));
        Ba.p[1] = __builtin_amdgcn_cvt_pkrtz(fmaxf(a1a[2], 0.f), fmaxf(a1a[3], 0.f));
        Bb.p[0] = __builtin_amdgcn_cvt_pkrtz(fmaxf(a1b[0], 0.f), fmaxf(a1b[1], 0.f));
        Bb.p[1] = __builtin_amdgcn_cvt_pkrtz(fmaxf(a1b[2], 0.f), fmaxf(a1b[3], 0.f));
        B2sA[l] = Ba.v;
        B2sB[l] = Bb.v;
    }

    // ---- Phase B: two independent serial recurrences, interleaved ----
    f16x4 H0 = {}, H1 = {};
    #pragma unroll
    for (int l = 0; l < LSEQ; ++l) {
        f32x4 a20 = __builtin_amdgcn_mfma_f32_16x16x16f16(A2, B2sA[l], rbp, 0, 0, 0);
        f32x4 a21 = __builtin_amdgcn_mfma_f32_16x16x16f16(A2, B2sB[l], rbp, 0, 0, 0);
        a20 = __builtin_amdgcn_mfma_f32_16x16x16f16(AU, H0, a20, 0, 0, 0);
        a21 = __builtin_amdgcn_mfma_f32_16x16x16f16(AU, H1, a21, 0, 0, 0);
        float t00 = __builtin_amdgcn_rcpf(1.f + __builtin_amdgcn_exp2f(a20[0]));
        float t01 = __builtin_amdgcn_rcpf(1.f + __builtin_amdgcn_exp2f(a20[1]));
        float t02 = __builtin_amdgcn_rcpf(1.f + __builtin_amdgcn_exp2f(a20[2]));
        float t03 = __builtin_amdgcn_rcpf(1.f + __builtin_amdgcn_exp2f(a20[3]));
        float t10 = __builtin_amdgcn_rcpf(1.f + __builtin_amdgcn_exp2f(a21[0]));
        float t11 = __builtin_amdgcn_rcpf(1.f + __builtin_amdgcn_exp2f(a21[1]));
        float t12 = __builtin_amdgcn_rcpf(1.f + __builtin_amdgcn_exp2f(a21[2]));
        float t13 = __builtin_amdgcn_rcpf(1.f + __builtin_amdgcn_exp2f(a21[3]));
        UB64 Hn0, Hn1;
        Hn0.p[0] = __builtin_amdgcn_cvt_pkrtz(fmaf(-2.f, t00, 1.f), fmaf(-2.f, t01, 1.f));
        Hn0.p[1] = __builtin_amdgcn_cvt_pkrtz(fmaf(-2.f, t02, 1.f), fmaf(-2.f, t03, 1.f));
        Hn1.p[0] = __builtin_amdgcn_cvt_pkrtz(fmaf(-2.f, t10, 1.f), fmaf(-2.f, t11, 1.f));
        Hn1.p[1] = __builtin_amdgcn_cvt_pkrtz(fmaf(-2.f, t12, 1.f), fmaf(-2.f, t13, 1.f));
        H0 = Hn0.v;
        H1 = Hn1.v;
    }

    // ---- head via MFMA ----
    f32x4 a30 = __builtin_amdgcn_mfma_f32_16x16x16f16(A3, H0, c3, 0, 0, 0);
    f32x4 a31 = __builtin_amdgcn_mfma_f32_16x16x16f16(A3, H1, c3, 0, 0, 0);
    float p0 = 0.f, p1 = 0.f;
    #pragma unroll
    for (int r = 0; r < 4; ++r) {
        p0 = fmaf(fmaxf(a30[r], 0.f), ow[r], p0);
        p1 = fmaf(fmaxf(a31[r], 0.f), ow[r], p1);
    }
    p0 += __shfl_xor(p0, 16); p0 += __shfl_xor(p0, 32);
    p1 += __shfl_xor(p1, 16); p1 += __shfl_xor(p1, 32);
    if (lane < 16) {
        out[BE + b16]      = p0 + ob;
        out[BE + 16 + b16] = p1 + ob;
    }
}

extern "C" void kernel_launch(void* const* d_in, const int* in_sizes, int n_in,
                              void* d_out, int out_size, void* d_ws, size_t ws_size,
                              hipStream_t stream) {
    const float* x      = (const float*)d_in[0];
    const float* conv_w = (const float*)d_in[1];
    const float* conv_b = (const float*)d_in[2];
    const float* rnn_w  = (const float*)d_in[3];
    const float* rnn_u  = (const float*)d_in[4];
    const float* rnn_b  = (const float*)d_in[5];
    const float* d1_w   = (const float*)d_in[6];
    const float* d1_b   = (const float*)d_in[7];
    const float* out_w  = (const float*)d_in[8];
    const float* out_b  = (const float*)d_in[9];
    float* out = (float*)d_out;

    const int B = out_size;                 // 262144
    const int grid = B / 32;                // 8192 single-wave blocks
    hybrid_fwd<<<grid, BLK, 0, stream>>>(x, conv_w, conv_b, rnn_w, rnn_u, rnn_b,
                                         d1_w, d1_b, out_w, out_b, out);
}